// Round 8
// baseline (23713.977 us; speedup 1.0000x reference)
//
#include <hip/hip_runtime.h>
#include <math.h>

namespace {

constexpr int B_ = 32, K_ = 512, L_ = 6, D_ = 2048, H_ = 16, HD_ = 128;
constexpr int OBS_ = 128, MAXS_ = 512, A_ = 10;
constexpr int NCH = 8;                        // 8 key-chunks of 64 keys (one block each)
constexpr float EPS = 1e-5f;
constexpr float INV_SCALE = 0.022097086912079608f; // 1/sqrt(2048)

struct Params {
  const float *x, *mem;
  const int *mask, *midx;
  const float *enc_w, *enc_b;
  const float *lnq_g, *lnq_b, *lnkv_g, *lnkv_b, *lnat_g, *lnat_b;
  const float *wq, *wk, *wv, *wo, *bo, *fc_w, *fc_b;
  const float *post_w, *post_b, *act_w, *act_b, *cri_w, *cri_b;
  float *out;
  float *pe, *h, *xr, *hid, *pm, *ps, *pctx;
};

__device__ __forceinline__ float wsum64(float v) {
  v += __shfl_xor(v, 32); v += __shfl_xor(v, 16); v += __shfl_xor(v, 8);
  v += __shfl_xor(v, 4);  v += __shfl_xor(v, 2);  v += __shfl_xor(v, 1);
  return v;
}

// ---------------- pe table + encoder ----------------
__global__ __launch_bounds__(512) void k_peenc(Params P) {
  const int g = blockIdx.x, t = threadIdx.x;
  int b = g >> 3, ec = g & 7;
  __shared__ float smem[OBS_];
  if (t < 32) ((float4*)smem)[t] = ((const float4*)(P.x + b * OBS_))[t];
  int half = t >> 8, tt = t & 255;
  int s = g + 256 * half;
  float seqv = (float)(MAXS_ - 1 - s);
  const float c = 13.287712379549449f / 1024.0f; // log2(10000)/1024
  #pragma unroll
  for (int r = 0; r < 8; ++r) {
    int j = tt + 256 * r;
    int i = (j < 1024) ? j : j - 1024;
    float inv = exp2f(-c * (float)i);
    float a = seqv * inv;
    P.pe[(size_t)s * D_ + j] = (j < 1024) ? sinf(a) : cosf(a);
  }
  __syncthreads();
  if (t < 256) {
    int e = ec * 256 + t;
    const float* wr = P.enc_w + (size_t)e * OBS_;
    float acc = 0.f;
    #pragma unroll
    for (int o = 0; o < OBS_; o += 4) {
      float4 w = *(const float4*)(wr + o);
      acc += w.x * smem[o] + w.y * smem[o + 1] + w.z * smem[o + 2] + w.w * smem[o + 3];
    }
    P.h[(size_t)b * D_ + e] = acc + P.enc_b[e];
  }
}

// ---------------- attention (q/Wk proj + flash + in-block cross-wave merge) ----------------
__global__ __launch_bounds__(512, 2) void k_attn(Params P, int l) {
  const int b = blockIdx.x, ch = blockIdx.y, t = threadIdx.x;
  const int lane = t & 63, wv = t >> 6;
  __shared__ float gs[D_], bs[D_], qsW[D_];
  __shared__ float rs[8], rq[8];
  const float* qg = P.lnq_g + (size_t)l * D_;
  const float* qb = P.lnq_b + (size_t)l * D_;
  const float* kg = P.lnkv_g + (size_t)l * D_;
  const float* kb = P.lnkv_b + (size_t)l * D_;
  const float* Wq = P.wq + (size_t)l * HD_ * HD_;
  const float* Wk = P.wk + (size_t)l * HD_ * HD_;

  float4 v0 = ((const float4*)(P.h + (size_t)b * D_))[t];

  // ---- LN(h) with lnq -> gs ----
  {
    float ls = v0.x + v0.y + v0.z + v0.w;
    float lq = v0.x * v0.x + v0.y * v0.y + v0.z * v0.z + v0.w * v0.w;
    ls = wsum64(ls); lq = wsum64(lq);
    if (lane == 0) { rs[wv] = ls; rq[wv] = lq; }
    __syncthreads();
    float sum = 0.f, sq = 0.f;
    #pragma unroll
    for (int w = 0; w < 8; ++w) { sum += rs[w]; sq += rq[w]; }
    float mean = sum * (1.f / D_);
    float rstd = rsqrtf(sq * (1.f / D_) - mean * mean + EPS);
    float4 g0 = *(const float4*)(qg + t * 4);
    float4 b0 = *(const float4*)(qb + t * 4);
    gs[t * 4 + 0] = (v0.x - mean) * rstd * g0.x + b0.x;
    gs[t * 4 + 1] = (v0.y - mean) * rstd * g0.y + b0.y;
    gs[t * 4 + 2] = (v0.z - mean) * rstd * g0.z + b0.z;
    gs[t * 4 + 3] = (v0.w - mean) * rstd * g0.w + b0.w;
  }
  __syncthreads();
  // ---- q = Wq . qn  (16 head-groups of 32 lanes) -> bs ----
  {
    int qid = t >> 5, li = t & 31;
    for (int e = 0; e < 128; ++e) {
      float4 w0 = *(const float4*)(Wq + (size_t)e * HD_ + li * 4);
      float4 a0 = *(const float4*)(gs + qid * HD_ + li * 4);
      float acc = w0.x * a0.x + w0.y * a0.y + w0.z * a0.z + w0.w * a0.w;
      acc += __shfl_xor(acc, 1); acc += __shfl_xor(acc, 2);
      acc += __shfl_xor(acc, 4); acc += __shfl_xor(acc, 8);
      acc += __shfl_xor(acc, 16);
      if (li == 0) bs[qid * HD_ + e] = acc;
    }
  }
  __syncthreads();
  // ---- qW = inv_scale * Wk^T q -> qsW ----
  {
    #pragma unroll
    for (int r = 0; r < 4; ++r) {
      int j = t + 512 * r;
      int hh = j >> 7, d = j & 127;
      const float* qv = bs + hh * HD_;
      float acc = 0.f;
      for (int e = 0; e < HD_; ++e) acc += qv[e] * Wk[(size_t)e * HD_ + d];
      qsW[j] = acc * INV_SCALE;
    }
  }
  __syncthreads();
  // ---- overwrite gs/bs with lnkv gamma/beta ----
  ((float4*)gs)[t] = ((const float4*)kg)[t];
  ((float4*)bs)[t] = ((const float4*)kb)[t];
  __syncthreads();

  // ---- wave-autonomous online softmax: wave wid handles keys ch*64+wid*8..+8 ----
  const int wid = wv, l64 = lane;
  const int hi = l64 >> 5, ll = l64 & 31;
  float m[8], s[8];
  float4 ctx[8];
  #pragma unroll
  for (int i = 0; i < 8; ++i) {
    m[i] = -INFINITY; s[i] = 0.f; ctx[i] = {0.f, 0.f, 0.f, 0.f};
  }
  const size_t browbase = ((size_t)b * K_) * (L_ * D_) + (size_t)l * D_;
  int kk0 = ch * 64 + wid * 8;
  for (int kk = kk0; kk < kk0 + 8; ++kk) {
    if (P.mask[b * K_ + kk] == 0) continue;   // wave-uniform
    int pidx = P.midx[b * K_ + kk];
    const float4* mp = (const float4*)(P.mem + browbase + (size_t)kk * (L_ * D_));
    const float4* pp = (const float4*)(P.pe + (size_t)pidx * D_);
    float4 xv[8];
    #pragma unroll
    for (int i = 0; i < 8; ++i) {
      float4 a = mp[i * 64 + l64];
      float4 c = pp[i * 64 + l64];
      xv[i] = {a.x + c.x, a.y + c.y, a.z + c.z, a.w + c.w};
    }
    float ls = 0.f, lq = 0.f;
    #pragma unroll
    for (int i = 0; i < 8; ++i) {
      ls += xv[i].x + xv[i].y + xv[i].z + xv[i].w;
      lq += xv[i].x * xv[i].x + xv[i].y * xv[i].y + xv[i].z * xv[i].z + xv[i].w * xv[i].w;
    }
    ls = wsum64(ls); lq = wsum64(lq);
    float mean = ls * (1.f / D_);
    float rstd = rsqrtf(lq * (1.f / D_) - mean * mean + EPS);
    #pragma unroll
    for (int i = 0; i < 8; ++i) {
      int idx = i * 64 + l64;
      float4 g4 = ((const float4*)gs)[idx];
      float4 b4 = ((const float4*)bs)[idx];
      float4 q4 = ((const float4*)qsW)[idx];
      float4 kv;
      kv.x = (xv[i].x - mean) * rstd * g4.x + b4.x;
      kv.y = (xv[i].y - mean) * rstd * g4.y + b4.y;
      kv.z = (xv[i].z - mean) * rstd * g4.z + b4.z;
      kv.w = (xv[i].w - mean) * rstd * g4.w + b4.w;
      float p = kv.x * q4.x + kv.y * q4.y + kv.z * q4.z + kv.w * q4.w;
      p += __shfl_xor(p, 1); p += __shfl_xor(p, 2); p += __shfl_xor(p, 4);
      p += __shfl_xor(p, 8); p += __shfl_xor(p, 16);
      float mn = fmaxf(m[i], p);
      float sc = __expf(m[i] - mn);
      float w = __expf(p - mn);
      s[i] = s[i] * sc + w;
      ctx[i].x = ctx[i].x * sc + w * kv.x;
      ctx[i].y = ctx[i].y * sc + w * kv.y;
      ctx[i].z = ctx[i].z * sc + w * kv.z;
      ctx[i].w = ctx[i].w * sc + w * kv.w;
      m[i] = mn;
    }
  }

  // ---- in-block cross-wave merge: 8 stages, one head-pair per stage ----
  float* ctxbuf = gs;
  float* mbuf = bs;
  float* sbuf = bs + 16;
  #pragma unroll
  for (int st = 0; st < 8; ++st) {
    __syncthreads();
    *(float4*)(ctxbuf + (wid * 2 + hi) * 128 + 4 * ll) = ctx[st];
    if (ll == 0) { mbuf[wid * 2 + hi] = m[st]; sbuf[wid * 2 + hi] = s[st]; }
    __syncthreads();
    if (t < 256) {
      int hi2 = t >> 7, d = t & 127;
      float M = -INFINITY;
      #pragma unroll
      for (int w = 0; w < 8; ++w) M = fmaxf(M, mbuf[w * 2 + hi2]);
      float ssum = 0.f, cacc = 0.f;
      #pragma unroll
      for (int w = 0; w < 8; ++w) {
        float mw = mbuf[w * 2 + hi2];
        float wc = (mw == -INFINITY) ? 0.f : __expf(mw - M);
        ssum += sbuf[w * 2 + hi2] * wc;
        cacc += ctxbuf[(w * 2 + hi2) * 128 + d] * wc;
      }
      int head = 2 * st + hi2;
      size_t base = (size_t)(b * H_ + head) * NCH + ch;
      P.pctx[base * HD_ + d] = cacc;
      if (d == 0) { P.pm[base] = M; P.ps[base] = ssum; }
    }
  }
}

// ---------- merge chunks + Wv + full-K Wo GEMM -> xr = Wo.opre + bo + h ----------
__global__ __launch_bounds__(512, 2) void k_womid(Params P, int l) {
  const int et = blockIdx.x, t = threadIdx.x;   // et 0..127, 16 rows each
  __shared__ float cn[32][132];
  __shared__ float xs[32][260];
  __shared__ float wbuf[32][2][8];
  __shared__ float sbuf[32][2];
  const float* Wv = P.wv + (size_t)l * HD_ * HD_;
  const float* Wo = P.wo + (size_t)l * D_ * D_;
  const float* bo_ = P.bo + (size_t)l * D_;
  const int b = t & 31, eg = t >> 5;
  const int row = et * 16 + eg;
  float acc = 0.f;

  for (int kc = 0; kc < 8; ++kc) {
    __syncthreads();     // protect wbuf/cn/xs from previous iteration's readers
    // merge weights for heads kc*2, kc*2+1
    {
      int bb = t >> 4, hh2 = (t >> 3) & 1, c = t & 7;
      int head = kc * 2 + hh2;
      size_t base = (size_t)(bb * H_ + head) * NCH;
      float mx = -INFINITY;
      #pragma unroll
      for (int c2 = 0; c2 < 8; ++c2) mx = fmaxf(mx, P.pm[base + c2]);
      float mv = P.pm[base + c];
      wbuf[bb][hh2][c] = (mv == -INFINITY) ? 0.f : __expf(mv - mx);
    }
    __syncthreads();
    if (t < 64) {
      int bb = t >> 1, hh2 = t & 1;
      int head = kc * 2 + hh2;
      size_t base = (size_t)(bb * H_ + head) * NCH;
      float stot = 0.f;
      #pragma unroll
      for (int c = 0; c < 8; ++c) stot += P.ps[base + c] * wbuf[bb][hh2][c];
      sbuf[bb][hh2] = (stot > 0.f) ? 1.f / stot : 0.f;
    }
    __syncthreads();
    for (int hh2 = 0; hh2 < 2; ++hh2) {
      int head = kc * 2 + hh2;
      #pragma unroll
      for (int r = 0; r < 8; ++r) {
        int flat = r * 512 + t;          // 0..4095
        int bb = flat >> 7, d = flat & 127;
        size_t base = (size_t)(bb * H_ + head) * NCH;
        float a = 0.f;
        #pragma unroll
        for (int c = 0; c < 8; ++c)
          a += P.pctx[(base + c) * HD_ + d] * wbuf[bb][hh2][c];
        cn[bb][d] = a * sbuf[bb][hh2];
      }
      __syncthreads();
      #pragma unroll
      for (int r = 0; r < 8; ++r) {
        int flat = r * 512 + t;
        int bb = flat >> 7, e = flat & 127;
        const float4* wr = (const float4*)(Wv + (size_t)e * HD_);
        float a = 0.f;
        #pragma unroll
        for (int d4 = 0; d4 < 32; ++d4) {
          float4 w4 = wr[d4];
          float4 c4 = *(const float4*)(&cn[bb][4 * d4]);
          a += w4.x * c4.x + w4.y * c4.y + w4.z * c4.z + w4.w * c4.w;
        }
        xs[bb][hh2 * 128 + e] = a;
      }
      __syncthreads();
    }
    // GEMM chunk: row (broadcast across 32 b-lanes), k-cols kc*256..+255
    const float* wrow = Wo + (size_t)row * D_ + kc * 256;
    for (int j = 0; j < 64; ++j) {
      float4 x4 = *(const float4*)&xs[b][4 * j];
      float4 w4 = *(const float4*)(wrow + 4 * j);
      acc += w4.x * x4.x + w4.y * x4.y + w4.z * x4.z + w4.w * x4.w;
    }
  }
  P.xr[(size_t)b * D_ + row] = acc + bo_[row] + P.h[(size_t)b * D_ + row];
}

// ---------- LN(xr) + full-K Fw GEMM -> h = relu(acc+Fb) + xr ----------
__global__ __launch_bounds__(512, 2) void k_fc(Params P, int l) {
  const int et = blockIdx.x, t = threadIdx.x;   // et 0..127, 16 rows each
  __shared__ float xs[32][260];
  __shared__ float ms[32], qsm[32];
  const float* ag = P.lnat_g + (size_t)l * D_;
  const float* ab = P.lnat_b + (size_t)l * D_;
  const float* fb = P.fc_b + (size_t)l * D_;
  const float* Fw = P.fc_w + (size_t)l * D_ * D_;

  // full-row stats for all 32 batches (redundant per block)
  {
    int bb = t >> 4, li = t & 15;
    const float4* xa = (const float4*)(P.xr + (size_t)bb * D_);
    float ls = 0.f, lq = 0.f;
    for (int i = 0; i < 32; ++i) {
      float4 a = xa[li + 16 * i];
      ls += a.x + a.y + a.z + a.w;
      lq += a.x * a.x + a.y * a.y + a.z * a.z + a.w * a.w;
    }
    ls += __shfl_xor(ls, 1); ls += __shfl_xor(ls, 2);
    ls += __shfl_xor(ls, 4); ls += __shfl_xor(ls, 8);
    lq += __shfl_xor(lq, 1); lq += __shfl_xor(lq, 2);
    lq += __shfl_xor(lq, 4); lq += __shfl_xor(lq, 8);
    if (li == 0) { ms[bb] = ls; qsm[bb] = lq; }
  }
  __syncthreads();

  const int b = t & 31, eg = t >> 5;
  const int row = et * 16 + eg;
  float acc = 0.f;
  for (int kc = 0; kc < 8; ++kc) {
    __syncthreads();
    #pragma unroll
    for (int r = 0; r < 16; ++r) {
      int flat = r * 512 + t;            // 0..8191
      int bb = flat >> 8, j = flat & 255;
      int col = kc * 256 + j;
      float a = P.xr[(size_t)bb * D_ + col];
      float mean = ms[bb] * (1.f / D_);
      float rstd = rsqrtf(qsm[bb] * (1.f / D_) - mean * mean + EPS);
      xs[bb][j] = (a - mean) * rstd * ag[col] + ab[col];
    }
    __syncthreads();
    const float* wrow = Fw + (size_t)row * D_ + kc * 256;
    for (int j = 0; j < 64; ++j) {
      float4 x4 = *(const float4*)&xs[b][4 * j];
      float4 w4 = *(const float4*)(wrow + 4 * j);
      acc += w4.x * x4.x + w4.y * x4.y + w4.z * x4.z + w4.w * x4.w;
    }
  }
  float xrv = P.xr[(size_t)b * D_ + row];
  P.h[(size_t)b * D_ + row] = fmaxf(acc + fb[row], 0.f) + xrv;
}

// ---------- post: hid = relu(post_w . h + post_b) ----------
__global__ __launch_bounds__(512, 2) void k_post(Params P) {
  const int et = blockIdx.x, t = threadIdx.x;
  __shared__ float xs[32][260];
  const int b = t & 31, eg = t >> 5;
  const int row = et * 16 + eg;
  float acc = 0.f;
  for (int kc = 0; kc < 8; ++kc) {
    __syncthreads();
    #pragma unroll
    for (int r = 0; r < 16; ++r) {
      int flat = r * 512 + t;
      int bb = flat >> 8, j = flat & 255;
      xs[bb][j] = P.h[(size_t)bb * D_ + kc * 256 + j];
    }
    __syncthreads();
    const float* wrow = P.post_w + (size_t)row * D_ + kc * 256;
    for (int j = 0; j < 64; ++j) {
      float4 x4 = *(const float4*)&xs[b][4 * j];
      float4 w4 = *(const float4*)(wrow + 4 * j);
      acc += w4.x * x4.x + w4.y * x4.y + w4.z * x4.z + w4.w * x4.w;
    }
  }
  P.hid[(size_t)b * D_ + row] = fmaxf(acc + P.post_b[row], 0.f);
}

// ---------- heads ----------
__global__ __launch_bounds__(512) void k_heads(Params P) {
  const int b = blockIdx.x, t = threadIdx.x;
  const int lane = t & 63, wv = t >> 6;
  __shared__ float smem[D_];
  ((float4*)smem)[t] = ((const float4*)(P.hid + (size_t)b * D_))[t];
  __syncthreads();
  for (int j = wv; j < A_ + 1; j += 8) {
    const float* wr = (j < A_) ? (P.act_w + (size_t)j * D_) : P.cri_w;
    float acc = 0.f;
    for (int i = lane; i < D_ / 4; i += 64) {
      float4 w4 = ((const float4*)wr)[i];
      float4 xv = ((const float4*)smem)[i];
      acc += w4.x * xv.x + w4.y * xv.y + w4.z * xv.z + w4.w * xv.w;
    }
    acc = wsum64(acc);
    if (lane == 0)
      P.out[b * (A_ + 1) + j] = acc + ((j < A_) ? P.act_b[j] : P.cri_b[0]);
  }
}

} // namespace

extern "C" void kernel_launch(void* const* d_in, const int* in_sizes, int n_in,
                              void* d_out, int out_size, void* d_ws, size_t ws_size,
                              hipStream_t stream) {
  (void)in_sizes; (void)n_in; (void)out_size; (void)ws_size;
  Params p;
  p.x      = (const float*)d_in[0];
  p.mem    = (const float*)d_in[1];
  p.mask   = (const int*)d_in[2];
  p.midx   = (const int*)d_in[3];
  p.enc_w  = (const float*)d_in[4];
  p.enc_b  = (const float*)d_in[5];
  p.lnq_g  = (const float*)d_in[6];
  p.lnq_b  = (const float*)d_in[7];
  p.lnkv_g = (const float*)d_in[8];
  p.lnkv_b = (const float*)d_in[9];
  p.lnat_g = (const float*)d_in[10];
  p.lnat_b = (const float*)d_in[11];
  p.wq     = (const float*)d_in[12];
  p.wk     = (const float*)d_in[13];
  p.wv     = (const float*)d_in[14];
  p.wo     = (const float*)d_in[15];
  p.bo     = (const float*)d_in[16];
  p.fc_w   = (const float*)d_in[17];
  p.fc_b   = (const float*)d_in[18];
  p.post_w = (const float*)d_in[19];
  p.post_b = (const float*)d_in[20];
  p.act_w  = (const float*)d_in[21];
  p.act_b  = (const float*)d_in[22];
  p.cri_w  = (const float*)d_in[23];
  p.cri_b  = (const float*)d_in[24];
  p.out    = (float*)d_out;

  float* ws = (float*)d_ws;
  size_t off = 0;
  p.pe   = ws + off; off += (size_t)MAXS_ * D_;
  p.h    = ws + off; off += (size_t)B_ * D_;
  p.xr   = ws + off; off += (size_t)B_ * D_;
  p.hid  = ws + off; off += (size_t)B_ * D_;
  p.pm   = ws + off; off += (size_t)B_ * H_ * NCH;
  p.ps   = ws + off; off += (size_t)B_ * H_ * NCH;
  p.pctx = ws + off; off += (size_t)B_ * H_ * NCH * HD_;

  hipLaunchKernelGGL(k_peenc, dim3(256), dim3(512), 0, stream, p);
  for (int l = 0; l < L_; ++l) {
    hipLaunchKernelGGL(k_attn, dim3(B_, NCH), dim3(512), 0, stream, p, l);
    hipLaunchKernelGGL(k_womid, dim3(128), dim3(512), 0, stream, p, l);
    hipLaunchKernelGGL(k_fc, dim3(128), dim3(512), 0, stream, p, l);
  }
  hipLaunchKernelGGL(k_post, dim3(128), dim3(512), 0, stream, p);
  hipLaunchKernelGGL(k_heads, dim3(B_), dim3(512), 0, stream, p);
}

// Round 9
// 4053.426 us; speedup vs baseline: 5.8504x; 5.8504x over previous
//
#include <hip/hip_runtime.h>
#include <math.h>

namespace {

constexpr int B_ = 32, K_ = 512, L_ = 6, D_ = 2048, H_ = 16, HD_ = 128;
constexpr int OBS_ = 128, MAXS_ = 512, A_ = 10;
constexpr int NCH = 8;                        // 8 key-chunks of 64 keys (one block each)
constexpr float EPS = 1e-5f;
constexpr float INV_SCALE = 0.022097086912079608f; // 1/sqrt(2048)

struct Params {
  const float *x, *mem;
  const int *mask, *midx;
  const float *enc_w, *enc_b;
  const float *lnq_g, *lnq_b, *lnkv_g, *lnkv_b, *lnat_g, *lnat_b;
  const float *wq, *wk, *wv, *wo, *bo, *fc_w, *fc_b;
  const float *post_w, *post_b, *act_w, *act_b, *cri_w, *cri_b;
  float *out;
  float *pe, *h, *xr, *part, *part2, *part3, *pm, *ps, *pctx;
};

__device__ __forceinline__ float wsum64(float v) {
  v += __shfl_xor(v, 32); v += __shfl_xor(v, 16); v += __shfl_xor(v, 8);
  v += __shfl_xor(v, 4);  v += __shfl_xor(v, 2);  v += __shfl_xor(v, 1);
  return v;
}

// ---------------- pe table + encoder ----------------
__global__ __launch_bounds__(512) void k_peenc(Params P) {
  const int g = blockIdx.x, t = threadIdx.x;
  int b = g >> 3, ec = g & 7;
  __shared__ float smem[OBS_];
  if (t < 32) ((float4*)smem)[t] = ((const float4*)(P.x + b * OBS_))[t];
  int half = t >> 8, tt = t & 255;
  int s = g + 256 * half;
  float seqv = (float)(MAXS_ - 1 - s);
  const float c = 13.287712379549449f / 1024.0f; // log2(10000)/1024
  #pragma unroll
  for (int r = 0; r < 8; ++r) {
    int j = tt + 256 * r;
    int i = (j < 1024) ? j : j - 1024;
    float inv = exp2f(-c * (float)i);
    float a = seqv * inv;
    P.pe[(size_t)s * D_ + j] = (j < 1024) ? sinf(a) : cosf(a);
  }
  __syncthreads();
  if (t < 256) {
    int e = ec * 256 + t;
    const float* wr = P.enc_w + (size_t)e * OBS_;
    float acc = 0.f;
    #pragma unroll
    for (int o = 0; o < OBS_; o += 4) {
      float4 w = *(const float4*)(wr + o);
      acc += w.x * smem[o] + w.y * smem[o + 1] + w.z * smem[o + 2] + w.w * smem[o + 3];
    }
    P.h[(size_t)b * D_ + e] = acc + P.enc_b[e];
  }
}

// ------- attention: x_l recompute from part2 + q/Wk proj + flash + in-block merge -------
__global__ __launch_bounds__(512, 2) void k_attn(Params P, int l) {
  const int b = blockIdx.x, ch = blockIdx.y, t = threadIdx.x;
  const int lane = t & 63, wv = t >> 6;
  __shared__ float gs[D_], bs[D_], qsW[D_];
  __shared__ float rs[8], rq[8];
  const float* qg = P.lnq_g + (size_t)l * D_;
  const float* qb = P.lnq_b + (size_t)l * D_;
  const float* kg = P.lnkv_g + (size_t)l * D_;
  const float* kb = P.lnkv_b + (size_t)l * D_;
  const float* Wq = P.wq + (size_t)l * HD_ * HD_;
  const float* Wk = P.wk + (size_t)l * HD_ * HD_;

  // ---- layer input x_l ----
  float4 v0;
  if (l == 0) {
    v0 = ((const float4*)(P.h + (size_t)b * D_))[t];
  } else {
    const float* fbp = P.fc_b + (size_t)(l - 1) * D_;
    float4 a = {0.f, 0.f, 0.f, 0.f};
    #pragma unroll
    for (int kcp = 0; kcp < 8; ++kcp) {
      float4 p = ((const float4*)(P.part2 + ((size_t)b * 8 + kcp) * D_))[t];
      a.x += p.x; a.y += p.y; a.z += p.z; a.w += p.w;
    }
    float4 fb4 = ((const float4*)fbp)[t];
    float4 xf = ((const float4*)(P.xr + (size_t)b * D_))[t];
    v0.x = fmaxf(a.x + fb4.x, 0.f) + xf.x;
    v0.y = fmaxf(a.y + fb4.y, 0.f) + xf.y;
    v0.z = fmaxf(a.z + fb4.z, 0.f) + xf.z;
    v0.w = fmaxf(a.w + fb4.w, 0.f) + xf.w;
    if (ch == 0) ((float4*)(P.h + (size_t)b * D_))[t] = v0;
  }

  // ---- LN(x_l) with lnq -> gs ----
  {
    float ls = v0.x + v0.y + v0.z + v0.w;
    float lq = v0.x * v0.x + v0.y * v0.y + v0.z * v0.z + v0.w * v0.w;
    ls = wsum64(ls); lq = wsum64(lq);
    if (lane == 0) { rs[wv] = ls; rq[wv] = lq; }
    __syncthreads();
    float sum = 0.f, sq = 0.f;
    #pragma unroll
    for (int w = 0; w < 8; ++w) { sum += rs[w]; sq += rq[w]; }
    float mean = sum * (1.f / D_);
    float rstd = rsqrtf(sq * (1.f / D_) - mean * mean + EPS);
    float4 g0 = *(const float4*)(qg + t * 4);
    float4 b0 = *(const float4*)(qb + t * 4);
    gs[t * 4 + 0] = (v0.x - mean) * rstd * g0.x + b0.x;
    gs[t * 4 + 1] = (v0.y - mean) * rstd * g0.y + b0.y;
    gs[t * 4 + 2] = (v0.z - mean) * rstd * g0.z + b0.z;
    gs[t * 4 + 3] = (v0.w - mean) * rstd * g0.w + b0.w;
  }
  __syncthreads();
  // ---- q = Wq . qn  (16 head-groups of 32 lanes) -> bs ----
  {
    int qid = t >> 5, li = t & 31;
    for (int e = 0; e < 128; ++e) {
      float4 w0 = *(const float4*)(Wq + (size_t)e * HD_ + li * 4);
      float4 a0 = *(const float4*)(gs + qid * HD_ + li * 4);
      float acc = w0.x * a0.x + w0.y * a0.y + w0.z * a0.z + w0.w * a0.w;
      acc += __shfl_xor(acc, 1); acc += __shfl_xor(acc, 2);
      acc += __shfl_xor(acc, 4); acc += __shfl_xor(acc, 8);
      acc += __shfl_xor(acc, 16);
      if (li == 0) bs[qid * HD_ + e] = acc;
    }
  }
  __syncthreads();
  // ---- qW = inv_scale * Wk^T q -> qsW ----
  {
    #pragma unroll
    for (int r = 0; r < 4; ++r) {
      int j = t + 512 * r;
      int hh = j >> 7, d = j & 127;
      const float* qv = bs + hh * HD_;
      float acc = 0.f;
      for (int e = 0; e < HD_; ++e) acc += qv[e] * Wk[(size_t)e * HD_ + d];
      qsW[j] = acc * INV_SCALE;
    }
  }
  __syncthreads();
  ((float4*)gs)[t] = ((const float4*)kg)[t];
  ((float4*)bs)[t] = ((const float4*)kb)[t];
  __syncthreads();

  // ---- wave-autonomous online softmax: wave wid handles keys ch*64+wid*8..+8 ----
  const int wid = wv, l64 = lane;
  const int hi = l64 >> 5, ll = l64 & 31;
  float m[8], s[8];
  float4 ctx[8];
  #pragma unroll
  for (int i = 0; i < 8; ++i) {
    m[i] = -INFINITY; s[i] = 0.f; ctx[i] = {0.f, 0.f, 0.f, 0.f};
  }
  const size_t browbase = ((size_t)b * K_) * (L_ * D_) + (size_t)l * D_;
  int kk0 = ch * 64 + wid * 8;
  for (int kk = kk0; kk < kk0 + 8; ++kk) {
    if (P.mask[b * K_ + kk] == 0) continue;   // wave-uniform
    int pidx = P.midx[b * K_ + kk];
    const float4* mp = (const float4*)(P.mem + browbase + (size_t)kk * (L_ * D_));
    const float4* pp = (const float4*)(P.pe + (size_t)pidx * D_);
    float4 xv[8];
    #pragma unroll
    for (int i = 0; i < 8; ++i) {
      float4 a = mp[i * 64 + l64];
      float4 c = pp[i * 64 + l64];
      xv[i] = {a.x + c.x, a.y + c.y, a.z + c.z, a.w + c.w};
    }
    float ls = 0.f, lq = 0.f;
    #pragma unroll
    for (int i = 0; i < 8; ++i) {
      ls += xv[i].x + xv[i].y + xv[i].z + xv[i].w;
      lq += xv[i].x * xv[i].x + xv[i].y * xv[i].y + xv[i].z * xv[i].z + xv[i].w * xv[i].w;
    }
    ls = wsum64(ls); lq = wsum64(lq);
    float mean = ls * (1.f / D_);
    float rstd = rsqrtf(lq * (1.f / D_) - mean * mean + EPS);
    #pragma unroll
    for (int i = 0; i < 8; ++i) {
      int idx = i * 64 + l64;
      float4 g4 = ((const float4*)gs)[idx];
      float4 b4 = ((const float4*)bs)[idx];
      float4 q4 = ((const float4*)qsW)[idx];
      float4 kv;
      kv.x = (xv[i].x - mean) * rstd * g4.x + b4.x;
      kv.y = (xv[i].y - mean) * rstd * g4.y + b4.y;
      kv.z = (xv[i].z - mean) * rstd * g4.z + b4.z;
      kv.w = (xv[i].w - mean) * rstd * g4.w + b4.w;
      float p = kv.x * q4.x + kv.y * q4.y + kv.z * q4.z + kv.w * q4.w;
      p += __shfl_xor(p, 1); p += __shfl_xor(p, 2); p += __shfl_xor(p, 4);
      p += __shfl_xor(p, 8); p += __shfl_xor(p, 16);
      float mn = fmaxf(m[i], p);
      float sc = __expf(m[i] - mn);
      float w = __expf(p - mn);
      s[i] = s[i] * sc + w;
      ctx[i].x = ctx[i].x * sc + w * kv.x;
      ctx[i].y = ctx[i].y * sc + w * kv.y;
      ctx[i].z = ctx[i].z * sc + w * kv.z;
      ctx[i].w = ctx[i].w * sc + w * kv.w;
      m[i] = mn;
    }
  }

  // ---- in-block cross-wave merge: 8 stages, one head-pair per stage ----
  float* ctxbuf = gs;
  float* mbuf = bs;
  float* sbuf = bs + 16;
  #pragma unroll
  for (int st = 0; st < 8; ++st) {
    __syncthreads();
    *(float4*)(ctxbuf + (wid * 2 + hi) * 128 + 4 * ll) = ctx[st];
    if (ll == 0) { mbuf[wid * 2 + hi] = m[st]; sbuf[wid * 2 + hi] = s[st]; }
    __syncthreads();
    if (t < 256) {
      int hi2 = t >> 7, d = t & 127;
      float M = -INFINITY;
      #pragma unroll
      for (int w = 0; w < 8; ++w) M = fmaxf(M, mbuf[w * 2 + hi2]);
      float ssum = 0.f, cacc = 0.f;
      #pragma unroll
      for (int w = 0; w < 8; ++w) {
        float mw = mbuf[w * 2 + hi2];
        float wc = (mw == -INFINITY) ? 0.f : __expf(mw - M);
        ssum += sbuf[w * 2 + hi2] * wc;
        cacc += ctxbuf[(w * 2 + hi2) * 128 + d] * wc;
      }
      int head = 2 * st + hi2;
      size_t base = (size_t)(b * H_ + head) * NCH + ch;
      P.pctx[base * HD_ + d] = cacc;
      if (d == 0) { P.pm[base] = M; P.ps[base] = ssum; }
    }
  }
}

// ------- merge + Wv + Wo-chunk GEMM -> part (no atomics) -------
__global__ __launch_bounds__(512, 2) void k_wo(Params P, int l) {
  const int et = blockIdx.x, kc = blockIdx.y, t = threadIdx.x;
  __shared__ float xs[32][260];
  __shared__ float cn[32][132];
  __shared__ float wbuf[32][2][8];
  __shared__ float sbuf[32][2];
  const float* Wv = P.wv + (size_t)l * HD_ * HD_;
  const float* Wo = P.wo + (size_t)l * D_ * D_;

  {
    int b = t >> 4, hh2 = (t >> 3) & 1, c = t & 7;
    int head = kc * 2 + hh2;
    size_t base = (size_t)(b * H_ + head) * NCH;
    float mx = -INFINITY;
    #pragma unroll
    for (int c2 = 0; c2 < 8; ++c2) mx = fmaxf(mx, P.pm[base + c2]);
    float mv = P.pm[base + c];
    wbuf[b][hh2][c] = (mv == -INFINITY) ? 0.f : __expf(mv - mx);
  }
  __syncthreads();
  if (t < 64) {
    int b = t >> 1, hh2 = t & 1;
    int head = kc * 2 + hh2;
    size_t base = (size_t)(b * H_ + head) * NCH;
    float stot = 0.f;
    #pragma unroll
    for (int c = 0; c < 8; ++c) stot += P.ps[base + c] * wbuf[b][hh2][c];
    sbuf[b][hh2] = (stot > 0.f) ? 1.f / stot : 0.f;
  }
  __syncthreads();

  for (int hh2 = 0; hh2 < 2; ++hh2) {
    int head = kc * 2 + hh2;
    #pragma unroll
    for (int r = 0; r < 8; ++r) {
      int flat = r * 512 + t;
      int b = flat >> 7, d = flat & 127;
      size_t base = (size_t)(b * H_ + head) * NCH;
      float acc = 0.f;
      #pragma unroll
      for (int c = 0; c < 8; ++c)
        acc += P.pctx[(base + c) * HD_ + d] * wbuf[b][hh2][c];
      cn[b][d] = acc * sbuf[b][hh2];
    }
    __syncthreads();
    #pragma unroll
    for (int r = 0; r < 8; ++r) {
      int flat = r * 512 + t;
      int b = flat >> 7, e = flat & 127;
      const float4* wr = (const float4*)(Wv + (size_t)e * HD_);
      float acc = 0.f;
      #pragma unroll
      for (int d4 = 0; d4 < 32; ++d4) {
        float4 w4 = wr[d4];
        float4 c4 = *(const float4*)(&cn[b][4 * d4]);
        acc += w4.x * c4.x + w4.y * c4.y + w4.z * c4.z + w4.w * c4.w;
      }
      xs[b][hh2 * 128 + e] = acc;
    }
    __syncthreads();
  }

  int b = t & 31, eg = t >> 5;
  const float* wbase = Wo + (size_t)(et * 64 + eg * 4) * D_ + kc * 256;
  float acc[4] = {0.f, 0.f, 0.f, 0.f};
  for (int j = 0; j < 64; ++j) {
    float4 x4 = *(const float4*)&xs[b][4 * j];
    #pragma unroll
    for (int i = 0; i < 4; ++i) {
      float4 w4 = *(const float4*)(wbase + (size_t)i * D_ + 4 * j);
      acc[i] += w4.x * x4.x + w4.y * x4.y + w4.z * x4.z + w4.w * x4.w;
    }
  }
  float4 o0 = {acc[0], acc[1], acc[2], acc[3]};
  *(float4*)(P.part + ((size_t)b * 8 + kc) * D_ + et * 64 + eg * 4) = o0;
}

// ------- stats + LN + Fw-chunk GEMM -> part2 ; et==0 writes xr slice -------
__global__ __launch_bounds__(512, 2) void k_fc(Params P, int l) {
  const int et = blockIdx.x, kc = blockIdx.y, t = threadIdx.x;
  __shared__ float xs[32][260];
  __shared__ float ms[32], qsm[32];
  const float* ag = P.lnat_g + (size_t)l * D_;
  const float* ab = P.lnat_b + (size_t)l * D_;
  const float* bo_ = P.bo + (size_t)l * D_;
  const float* fb = P.fc_b + (size_t)l * D_;
  const float* Fw = P.fc_w + (size_t)l * D_ * D_;
  (void)fb;

  // full-row stats of xr = sum(part)+bo+h for all 32 b (redundant per block, L2-resident)
  {
    int bb = t >> 4, li = t & 15;
    const float4* bo4 = (const float4*)bo_;
    const float4* h4p = (const float4*)(P.h + (size_t)bb * D_);
    float ls = 0.f, lq = 0.f;
    for (int i = 0; i < 32; ++i) {
      int j = li + 16 * i;
      float4 a = bo4[j];
      float4 hh = h4p[j];
      a.x += hh.x; a.y += hh.y; a.z += hh.z; a.w += hh.w;
      #pragma unroll
      for (int kcp = 0; kcp < 8; ++kcp) {
        float4 p = ((const float4*)(P.part + ((size_t)bb * 8 + kcp) * D_))[j];
        a.x += p.x; a.y += p.y; a.z += p.z; a.w += p.w;
      }
      ls += a.x + a.y + a.z + a.w;
      lq += a.x * a.x + a.y * a.y + a.z * a.z + a.w * a.w;
    }
    ls += __shfl_xor(ls, 1); ls += __shfl_xor(ls, 2);
    ls += __shfl_xor(ls, 4); ls += __shfl_xor(ls, 8);
    lq += __shfl_xor(lq, 1); lq += __shfl_xor(lq, 2);
    lq += __shfl_xor(lq, 4); lq += __shfl_xor(lq, 8);
    if (li == 0) { ms[bb] = ls; qsm[bb] = lq; }
  }
  __syncthreads();

  // stage LN slice for cols kc*256..+256 ; et==0 writes xr slice
  #pragma unroll
  for (int r = 0; r < 16; ++r) {
    int flat = r * 512 + t;
    int bb = flat >> 8, j = flat & 255;
    int col = kc * 256 + j;
    float a = bo_[col] + P.h[(size_t)bb * D_ + col];
    #pragma unroll
    for (int kcp = 0; kcp < 8; ++kcp)
      a += P.part[((size_t)bb * 8 + kcp) * D_ + col];
    if (et == 0) P.xr[(size_t)bb * D_ + col] = a;
    float mean = ms[bb] * (1.f / D_);
    float rstd = rsqrtf(qsm[bb] * (1.f / D_) - mean * mean + EPS);
    xs[bb][j] = (a - mean) * rstd * ag[col] + ab[col];
  }
  __syncthreads();

  int b = t & 31, eg = t >> 5;
  const float* wbase = Fw + (size_t)(et * 64 + eg * 4) * D_ + kc * 256;
  float acc[4] = {0.f, 0.f, 0.f, 0.f};
  for (int j = 0; j < 64; ++j) {
    float4 x4 = *(const float4*)&xs[b][4 * j];
    #pragma unroll
    for (int i = 0; i < 4; ++i) {
      float4 w4 = *(const float4*)(wbase + (size_t)i * D_ + 4 * j);
      acc[i] += w4.x * x4.x + w4.y * x4.y + w4.z * x4.z + w4.w * x4.w;
    }
  }
  float4 o0 = {acc[0], acc[1], acc[2], acc[3]};
  *(float4*)(P.part2 + ((size_t)b * 8 + kc) * D_ + et * 64 + eg * 4) = o0;
}

// ------- post: x6 = relu(sum(part2)+fb5)+xr ; post_w-chunk GEMM -> part3 -------
__global__ __launch_bounds__(512, 2) void k_post(Params P) {
  const int et = blockIdx.x, kc = blockIdx.y, t = threadIdx.x;
  __shared__ float xs[32][260];
  const float* fb5 = P.fc_b + (size_t)(L_ - 1) * D_;
  #pragma unroll
  for (int r = 0; r < 16; ++r) {
    int flat = r * 512 + t;
    int bb = flat >> 8, j = flat & 255;
    int col = kc * 256 + j;
    float a = fb5[col];
    #pragma unroll
    for (int kcp = 0; kcp < 8; ++kcp)
      a += P.part2[((size_t)bb * 8 + kcp) * D_ + col];
    xs[bb][j] = fmaxf(a, 0.f) + P.xr[(size_t)bb * D_ + col];
  }
  __syncthreads();
  int b = t & 31, eg = t >> 5;
  const float* wbase = P.post_w + (size_t)(et * 64 + eg * 4) * D_ + kc * 256;
  float acc[4] = {0.f, 0.f, 0.f, 0.f};
  for (int j = 0; j < 64; ++j) {
    float4 x4 = *(const float4*)&xs[b][4 * j];
    #pragma unroll
    for (int i = 0; i < 4; ++i) {
      float4 w4 = *(const float4*)(wbase + (size_t)i * D_ + 4 * j);
      acc[i] += w4.x * x4.x + w4.y * x4.y + w4.z * x4.z + w4.w * x4.w;
    }
  }
  float4 o0 = {acc[0], acc[1], acc[2], acc[3]};
  *(float4*)(P.part3 + ((size_t)b * 8 + kc) * D_ + et * 64 + eg * 4) = o0;
}

// ------- heads: hid = relu(sum(part3)+pb); actor/critic dots -------
__global__ __launch_bounds__(512) void k_heads(Params P) {
  const int b = blockIdx.x, t = threadIdx.x;
  const int lane = t & 63, wv = t >> 6;
  __shared__ float smem[D_];
  {
    float4 a = ((const float4*)P.post_b)[t];
    #pragma unroll
    for (int kcp = 0; kcp < 8; ++kcp) {
      float4 p = ((const float4*)(P.part3 + ((size_t)b * 8 + kcp) * D_))[t];
      a.x += p.x; a.y += p.y; a.z += p.z; a.w += p.w;
    }
    a.x = fmaxf(a.x, 0.f); a.y = fmaxf(a.y, 0.f);
    a.z = fmaxf(a.z, 0.f); a.w = fmaxf(a.w, 0.f);
    ((float4*)smem)[t] = a;
  }
  __syncthreads();
  for (int j = wv; j < A_ + 1; j += 8) {
    const float* wr = (j < A_) ? (P.act_w + (size_t)j * D_) : P.cri_w;
    float acc = 0.f;
    for (int i = lane; i < D_ / 4; i += 64) {
      float4 w4 = ((const float4*)wr)[i];
      float4 xv = ((const float4*)smem)[i];
      acc += w4.x * xv.x + w4.y * xv.y + w4.z * xv.z + w4.w * xv.w;
    }
    acc = wsum64(acc);
    if (lane == 0)
      P.out[b * (A_ + 1) + j] = acc + ((j < A_) ? P.act_b[j] : P.cri_b[0]);
  }
}

} // namespace

extern "C" void kernel_launch(void* const* d_in, const int* in_sizes, int n_in,
                              void* d_out, int out_size, void* d_ws, size_t ws_size,
                              hipStream_t stream) {
  (void)in_sizes; (void)n_in; (void)out_size; (void)ws_size;
  Params p;
  p.x      = (const float*)d_in[0];
  p.mem    = (const float*)d_in[1];
  p.mask   = (const int*)d_in[2];
  p.midx   = (const int*)d_in[3];
  p.enc_w  = (const float*)d_in[4];
  p.enc_b  = (const float*)d_in[5];
  p.lnq_g  = (const float*)d_in[6];
  p.lnq_b  = (const float*)d_in[7];
  p.lnkv_g = (const float*)d_in[8];
  p.lnkv_b = (const float*)d_in[9];
  p.lnat_g = (const float*)d_in[10];
  p.lnat_b = (const float*)d_in[11];
  p.wq     = (const float*)d_in[12];
  p.wk     = (const float*)d_in[13];
  p.wv     = (const float*)d_in[14];
  p.wo     = (const float*)d_in[15];
  p.bo     = (const float*)d_in[16];
  p.fc_w   = (const float*)d_in[17];
  p.fc_b   = (const float*)d_in[18];
  p.post_w = (const float*)d_in[19];
  p.post_b = (const float*)d_in[20];
  p.act_w  = (const float*)d_in[21];
  p.act_b  = (const float*)d_in[22];
  p.cri_w  = (const float*)d_in[23];
  p.cri_b  = (const float*)d_in[24];
  p.out    = (float*)d_out;

  float* ws = (float*)d_ws;
  size_t off = 0;
  p.pe    = ws + off; off += (size_t)MAXS_ * D_;
  p.h     = ws + off; off += (size_t)B_ * D_;
  p.xr    = ws + off; off += (size_t)B_ * D_;
  p.part  = ws + off; off += (size_t)B_ * 8 * D_;
  p.part2 = ws + off; off += (size_t)B_ * 8 * D_;
  p.part3 = ws + off; off += (size_t)B_ * 8 * D_;
  p.pm    = ws + off; off += (size_t)B_ * H_ * NCH;
  p.ps    = ws + off; off += (size_t)B_ * H_ * NCH;
  p.pctx  = ws + off; off += (size_t)B_ * H_ * NCH * HD_;

  hipLaunchKernelGGL(k_peenc, dim3(256), dim3(512), 0, stream, p);
  for (int l = 0; l < L_; ++l) {
    hipLaunchKernelGGL(k_attn, dim3(B_, NCH), dim3(512), 0, stream, p, l);
    hipLaunchKernelGGL(k_wo, dim3(B_, 8), dim3(512), 0, stream, p, l);
    hipLaunchKernelGGL(k_fc, dim3(B_, 8), dim3(512), 0, stream, p, l);
  }
  hipLaunchKernelGGL(k_post, dim3(B_, 8), dim3(512), 0, stream, p);
  hipLaunchKernelGGL(k_heads, dim3(B_), dim3(512), 0, stream, p);
}

// Round 10
// 1659.749 us; speedup vs baseline: 14.2877x; 2.4422x over previous
//
#include <hip/hip_runtime.h>
#include <math.h>

namespace {

constexpr int B_ = 32, K_ = 512, L_ = 6, D_ = 2048, H_ = 16, HD_ = 128;
constexpr int OBS_ = 128, MAXS_ = 512, A_ = 10;
constexpr int NCH = 8;                        // 8 key-chunks of 64 keys (one block each)
constexpr float EPS = 1e-5f;
constexpr float INV_SCALE = 0.022097086912079608f; // 1/sqrt(2048)

struct Params {
  const float *x, *mem;
  const int *mask, *midx;
  const float *enc_w, *enc_b;
  const float *lnq_g, *lnq_b, *lnkv_g, *lnkv_b, *lnat_g, *lnat_b;
  const float *wq, *wk, *wv, *wo, *bo, *fc_w, *fc_b;
  const float *post_w, *post_b, *act_w, *act_b, *cri_w, *cri_b;
  float *out;
  float *pe, *h, *xr, *part, *part2, *part3, *pm, *ps, *pctx;
};

__device__ __forceinline__ float wsum64(float v) {
  v += __shfl_xor(v, 32); v += __shfl_xor(v, 16); v += __shfl_xor(v, 8);
  v += __shfl_xor(v, 4);  v += __shfl_xor(v, 2);  v += __shfl_xor(v, 1);
  return v;
}

// ---------------- pe table + encoder ----------------
__global__ __launch_bounds__(512) void k_peenc(Params P) {
  const int g = blockIdx.x, t = threadIdx.x;
  int b = g >> 3, ec = g & 7;
  __shared__ float smem[OBS_];
  if (t < 32) ((float4*)smem)[t] = ((const float4*)(P.x + b * OBS_))[t];
  int half = t >> 8, tt = t & 255;
  int s = g + 256 * half;
  float seqv = (float)(MAXS_ - 1 - s);
  const float c = 13.287712379549449f / 1024.0f; // log2(10000)/1024
  #pragma unroll
  for (int r = 0; r < 8; ++r) {
    int j = tt + 256 * r;
    int i = (j < 1024) ? j : j - 1024;
    float inv = exp2f(-c * (float)i);
    float a = seqv * inv;
    P.pe[(size_t)s * D_ + j] = (j < 1024) ? sinf(a) : cosf(a);
  }
  __syncthreads();
  if (t < 256) {
    int e = ec * 256 + t;
    const float* wr = P.enc_w + (size_t)e * OBS_;
    float acc = 0.f;
    #pragma unroll
    for (int o = 0; o < OBS_; o += 4) {
      float4 w = *(const float4*)(wr + o);
      acc += w.x * smem[o] + w.y * smem[o + 1] + w.z * smem[o + 2] + w.w * smem[o + 3];
    }
    P.h[(size_t)b * D_ + e] = acc + P.enc_b[e];
  }
}

// ------- attention: x_l recompute from part2 + q/Wk proj + flash + in-block merge -------
__global__ __launch_bounds__(512, 2) void k_attn(Params P, int l) {
  const int b = blockIdx.x, ch = blockIdx.y, t = threadIdx.x;
  const int lane = t & 63, wv = t >> 6;
  __shared__ float gs[D_], bs[D_], qsW[D_];
  __shared__ float rs[8], rq[8];
  const float* qg = P.lnq_g + (size_t)l * D_;
  const float* qb = P.lnq_b + (size_t)l * D_;
  const float* kg = P.lnkv_g + (size_t)l * D_;
  const float* kb = P.lnkv_b + (size_t)l * D_;
  const float* Wq = P.wq + (size_t)l * HD_ * HD_;
  const float* Wk = P.wk + (size_t)l * HD_ * HD_;

  // ---- layer input x_l ----
  float4 v0;
  if (l == 0) {
    v0 = ((const float4*)(P.h + (size_t)b * D_))[t];
  } else {
    const float* fbp = P.fc_b + (size_t)(l - 1) * D_;
    float4 a = {0.f, 0.f, 0.f, 0.f};
    #pragma unroll
    for (int kcp = 0; kcp < 8; ++kcp) {
      float4 p = ((const float4*)(P.part2 + ((size_t)b * 8 + kcp) * D_))[t];
      a.x += p.x; a.y += p.y; a.z += p.z; a.w += p.w;
    }
    float4 fb4 = ((const float4*)fbp)[t];
    float4 xf = ((const float4*)(P.xr + (size_t)b * D_))[t];
    v0.x = fmaxf(a.x + fb4.x, 0.f) + xf.x;
    v0.y = fmaxf(a.y + fb4.y, 0.f) + xf.y;
    v0.z = fmaxf(a.z + fb4.z, 0.f) + xf.z;
    v0.w = fmaxf(a.w + fb4.w, 0.f) + xf.w;
    if (ch == 0) ((float4*)(P.h + (size_t)b * D_))[t] = v0;
  }

  // ---- LN(x_l) with lnq -> gs ----
  {
    float ls = v0.x + v0.y + v0.z + v0.w;
    float lq = v0.x * v0.x + v0.y * v0.y + v0.z * v0.z + v0.w * v0.w;
    ls = wsum64(ls); lq = wsum64(lq);
    if (lane == 0) { rs[wv] = ls; rq[wv] = lq; }
    __syncthreads();
    float sum = 0.f, sq = 0.f;
    #pragma unroll
    for (int w = 0; w < 8; ++w) { sum += rs[w]; sq += rq[w]; }
    float mean = sum * (1.f / D_);
    float rstd = rsqrtf(sq * (1.f / D_) - mean * mean + EPS);
    float4 g0 = *(const float4*)(qg + t * 4);
    float4 b0 = *(const float4*)(qb + t * 4);
    gs[t * 4 + 0] = (v0.x - mean) * rstd * g0.x + b0.x;
    gs[t * 4 + 1] = (v0.y - mean) * rstd * g0.y + b0.y;
    gs[t * 4 + 2] = (v0.z - mean) * rstd * g0.z + b0.z;
    gs[t * 4 + 3] = (v0.w - mean) * rstd * g0.w + b0.w;
  }
  __syncthreads();
  // ---- q = Wq . qn  (16 head-groups of 32 lanes) -> bs ----
  {
    int qid = t >> 5, li = t & 31;
    for (int e = 0; e < 128; ++e) {
      float4 w0 = *(const float4*)(Wq + (size_t)e * HD_ + li * 4);
      float4 a0 = *(const float4*)(gs + qid * HD_ + li * 4);
      float acc = w0.x * a0.x + w0.y * a0.y + w0.z * a0.z + w0.w * a0.w;
      acc += __shfl_xor(acc, 1); acc += __shfl_xor(acc, 2);
      acc += __shfl_xor(acc, 4); acc += __shfl_xor(acc, 8);
      acc += __shfl_xor(acc, 16);
      if (li == 0) bs[qid * HD_ + e] = acc;
    }
  }
  __syncthreads();
  // ---- qW = inv_scale * Wk^T q -> qsW ----
  {
    #pragma unroll
    for (int r = 0; r < 4; ++r) {
      int j = t + 512 * r;
      int hh = j >> 7, d = j & 127;
      const float* qv = bs + hh * HD_;
      float acc = 0.f;
      for (int e = 0; e < HD_; ++e) acc += qv[e] * Wk[(size_t)e * HD_ + d];
      qsW[j] = acc * INV_SCALE;
    }
  }
  __syncthreads();
  ((float4*)gs)[t] = ((const float4*)kg)[t];
  ((float4*)bs)[t] = ((const float4*)kb)[t];
  __syncthreads();

  // ---- wave-autonomous online softmax: wave wid handles keys ch*64+wid*8..+8 ----
  const int wid = wv, l64 = lane;
  const int hi = l64 >> 5, ll = l64 & 31;
  float m[8], s[8];
  float4 ctx[8];
  #pragma unroll
  for (int i = 0; i < 8; ++i) {
    m[i] = -INFINITY; s[i] = 0.f; ctx[i] = {0.f, 0.f, 0.f, 0.f};
  }
  const size_t browbase = ((size_t)b * K_) * (L_ * D_) + (size_t)l * D_;
  int kk0 = ch * 64 + wid * 8;
  for (int kk = kk0; kk < kk0 + 8; ++kk) {
    if (P.mask[b * K_ + kk] == 0) continue;   // wave-uniform
    int pidx = P.midx[b * K_ + kk];
    const float4* mp = (const float4*)(P.mem + browbase + (size_t)kk * (L_ * D_));
    const float4* pp = (const float4*)(P.pe + (size_t)pidx * D_);
    float4 xv[8];
    #pragma unroll
    for (int i = 0; i < 8; ++i) {
      float4 a = mp[i * 64 + l64];
      float4 c = pp[i * 64 + l64];
      xv[i] = {a.x + c.x, a.y + c.y, a.z + c.z, a.w + c.w};
    }
    float ls = 0.f, lq = 0.f;
    #pragma unroll
    for (int i = 0; i < 8; ++i) {
      ls += xv[i].x + xv[i].y + xv[i].z + xv[i].w;
      lq += xv[i].x * xv[i].x + xv[i].y * xv[i].y + xv[i].z * xv[i].z + xv[i].w * xv[i].w;
    }
    ls = wsum64(ls); lq = wsum64(lq);
    float mean = ls * (1.f / D_);
    float rstd = rsqrtf(lq * (1.f / D_) - mean * mean + EPS);
    #pragma unroll
    for (int i = 0; i < 8; ++i) {
      int idx = i * 64 + l64;
      float4 g4 = ((const float4*)gs)[idx];
      float4 b4 = ((const float4*)bs)[idx];
      float4 q4 = ((const float4*)qsW)[idx];
      float4 kv;
      kv.x = (xv[i].x - mean) * rstd * g4.x + b4.x;
      kv.y = (xv[i].y - mean) * rstd * g4.y + b4.y;
      kv.z = (xv[i].z - mean) * rstd * g4.z + b4.z;
      kv.w = (xv[i].w - mean) * rstd * g4.w + b4.w;
      float p = kv.x * q4.x + kv.y * q4.y + kv.z * q4.z + kv.w * q4.w;
      p += __shfl_xor(p, 1); p += __shfl_xor(p, 2); p += __shfl_xor(p, 4);
      p += __shfl_xor(p, 8); p += __shfl_xor(p, 16);
      float mn = fmaxf(m[i], p);
      float sc = __expf(m[i] - mn);
      float w = __expf(p - mn);
      s[i] = s[i] * sc + w;
      ctx[i].x = ctx[i].x * sc + w * kv.x;
      ctx[i].y = ctx[i].y * sc + w * kv.y;
      ctx[i].z = ctx[i].z * sc + w * kv.z;
      ctx[i].w = ctx[i].w * sc + w * kv.w;
      m[i] = mn;
    }
  }

  // ---- in-block cross-wave merge: 8 stages, one head-pair per stage ----
  float* ctxbuf = gs;
  float* mbuf = bs;
  float* sbuf = bs + 16;
  #pragma unroll
  for (int st = 0; st < 8; ++st) {
    __syncthreads();
    *(float4*)(ctxbuf + (wid * 2 + hi) * 128 + 4 * ll) = ctx[st];
    if (ll == 0) { mbuf[wid * 2 + hi] = m[st]; sbuf[wid * 2 + hi] = s[st]; }
    __syncthreads();
    if (t < 256) {
      int hi2 = t >> 7, d = t & 127;
      float M = -INFINITY;
      #pragma unroll
      for (int w = 0; w < 8; ++w) M = fmaxf(M, mbuf[w * 2 + hi2]);
      float ssum = 0.f, cacc = 0.f;
      #pragma unroll
      for (int w = 0; w < 8; ++w) {
        float mw = mbuf[w * 2 + hi2];
        float wc = (mw == -INFINITY) ? 0.f : __expf(mw - M);
        ssum += sbuf[w * 2 + hi2] * wc;
        cacc += ctxbuf[(w * 2 + hi2) * 128 + d] * wc;
      }
      int head = 2 * st + hi2;
      size_t base = (size_t)(b * H_ + head) * NCH + ch;
      P.pctx[base * HD_ + d] = cacc;
      if (d == 0) { P.pm[base] = M; P.ps[base] = ssum; }
    }
  }
}

// ------- merge + Wv (broadcast) + Wo-chunk GEMM -> part; XCD-aware 1-D grid -------
__global__ __launch_bounds__(512, 2) void k_wo(Params P, int l) {
  const int g = blockIdx.x, t = threadIdx.x;
  const int et = g >> 3, kc = g & 7;   // g%8==kc -> same weight col-slice per XCD
  __shared__ float xs[32][260];
  __shared__ float cn[32][132];
  __shared__ float wbuf[32][2][8];
  __shared__ float sbuf[32][2];
  const float* Wv = P.wv + (size_t)l * HD_ * HD_;
  const float* Wo = P.wo + (size_t)l * D_ * D_;

  {
    int b = t >> 4, hh2 = (t >> 3) & 1, c = t & 7;
    int head = kc * 2 + hh2;
    size_t base = (size_t)(b * H_ + head) * NCH;
    float mx = -INFINITY;
    #pragma unroll
    for (int c2 = 0; c2 < 8; ++c2) mx = fmaxf(mx, P.pm[base + c2]);
    float mv = P.pm[base + c];
    wbuf[b][hh2][c] = (mv == -INFINITY) ? 0.f : __expf(mv - mx);
  }
  __syncthreads();
  if (t < 64) {
    int b = t >> 1, hh2 = t & 1;
    int head = kc * 2 + hh2;
    size_t base = (size_t)(b * H_ + head) * NCH;
    float stot = 0.f;
    #pragma unroll
    for (int c = 0; c < 8; ++c) stot += P.ps[base + c] * wbuf[b][hh2][c];
    sbuf[b][hh2] = (stot > 0.f) ? 1.f / stot : 0.f;
  }
  __syncthreads();

  for (int hh2 = 0; hh2 < 2; ++hh2) {
    int head = kc * 2 + hh2;
    #pragma unroll
    for (int r = 0; r < 8; ++r) {
      int flat = r * 512 + t;
      int b = flat >> 7, d = flat & 127;
      size_t base = (size_t)(b * H_ + head) * NCH;
      float acc = 0.f;
      #pragma unroll
      for (int c = 0; c < 8; ++c)
        acc += P.pctx[(base + c) * HD_ + d] * wbuf[b][hh2][c];
      cn[b][d] = acc * sbuf[b][hh2];
    }
    __syncthreads();
    // Wv matvec, broadcast reads: thread (b2 = t&31, eg2 = t>>5) computes e = eg2*8+er
    {
      int b2 = t & 31, eg2 = t >> 5;
      #pragma unroll
      for (int er = 0; er < 8; ++er) {
        int e = eg2 * 8 + er;
        const float4* wr = (const float4*)(Wv + (size_t)e * HD_);
        float acc = 0.f;
        #pragma unroll
        for (int d4 = 0; d4 < 32; ++d4) {
          float4 w4 = wr[d4];
          float4 c4 = *(const float4*)(&cn[b2][4 * d4]);
          acc += w4.x * c4.x + w4.y * c4.y + w4.z * c4.z + w4.w * c4.w;
        }
        xs[b2][hh2 * 128 + e] = acc;
      }
    }
    __syncthreads();
  }

  int b = t & 31, eg = t >> 5;
  const float* wbase = Wo + (size_t)(et * 64 + eg * 4) * D_ + kc * 256;
  float acc[4] = {0.f, 0.f, 0.f, 0.f};
  for (int j = 0; j < 64; ++j) {
    float4 x4 = *(const float4*)&xs[b][4 * j];
    #pragma unroll
    for (int i = 0; i < 4; ++i) {
      float4 w4 = *(const float4*)(wbase + (size_t)i * D_ + 4 * j);
      acc[i] += w4.x * x4.x + w4.y * x4.y + w4.z * x4.z + w4.w * x4.w;
    }
  }
  float4 o0 = {acc[0], acc[1], acc[2], acc[3]};
  *(float4*)(P.part + ((size_t)b * 8 + kc) * D_ + et * 64 + eg * 4) = o0;
}

// ------- stats + LN + Fw-chunk GEMM -> part2 ; et==0 writes xr slice; XCD 1-D grid -------
__global__ __launch_bounds__(512, 2) void k_fc(Params P, int l) {
  const int g = blockIdx.x, t = threadIdx.x;
  const int et = g >> 3, kc = g & 7;
  __shared__ float xs[32][260];
  __shared__ float ms[32], qsm[32];
  const float* ag = P.lnat_g + (size_t)l * D_;
  const float* ab = P.lnat_b + (size_t)l * D_;
  const float* bo_ = P.bo + (size_t)l * D_;
  const float* Fw = P.fc_w + (size_t)l * D_ * D_;

  // full-row stats of xr = sum(part)+bo+h for all 32 b (redundant per block, L2-resident)
  {
    int bb = t >> 4, li = t & 15;
    const float4* bo4 = (const float4*)bo_;
    const float4* h4p = (const float4*)(P.h + (size_t)bb * D_);
    float ls = 0.f, lq = 0.f;
    for (int i = 0; i < 32; ++i) {
      int j = li + 16 * i;
      float4 a = bo4[j];
      float4 hh = h4p[j];
      a.x += hh.x; a.y += hh.y; a.z += hh.z; a.w += hh.w;
      #pragma unroll
      for (int kcp = 0; kcp < 8; ++kcp) {
        float4 p = ((const float4*)(P.part + ((size_t)bb * 8 + kcp) * D_))[j];
        a.x += p.x; a.y += p.y; a.z += p.z; a.w += p.w;
      }
      ls += a.x + a.y + a.z + a.w;
      lq += a.x * a.x + a.y * a.y + a.z * a.z + a.w * a.w;
    }
    ls += __shfl_xor(ls, 1); ls += __shfl_xor(ls, 2);
    ls += __shfl_xor(ls, 4); ls += __shfl_xor(ls, 8);
    lq += __shfl_xor(lq, 1); lq += __shfl_xor(lq, 2);
    lq += __shfl_xor(lq, 4); lq += __shfl_xor(lq, 8);
    if (li == 0) { ms[bb] = ls; qsm[bb] = lq; }
  }
  __syncthreads();

  // stage LN slice for cols kc*256..+256 ; et==0 writes xr slice
  #pragma unroll
  for (int r = 0; r < 16; ++r) {
    int flat = r * 512 + t;
    int bb = flat >> 8, j = flat & 255;
    int col = kc * 256 + j;
    float a = bo_[col] + P.h[(size_t)bb * D_ + col];
    #pragma unroll
    for (int kcp = 0; kcp < 8; ++kcp)
      a += P.part[((size_t)bb * 8 + kcp) * D_ + col];
    if (et == 0) P.xr[(size_t)bb * D_ + col] = a;
    float mean = ms[bb] * (1.f / D_);
    float rstd = rsqrtf(qsm[bb] * (1.f / D_) - mean * mean + EPS);
    xs[bb][j] = (a - mean) * rstd * ag[col] + ab[col];
  }
  __syncthreads();

  int b = t & 31, eg = t >> 5;
  const float* wbase = Fw + (size_t)(et * 64 + eg * 4) * D_ + kc * 256;
  float acc[4] = {0.f, 0.f, 0.f, 0.f};
  for (int j = 0; j < 64; ++j) {
    float4 x4 = *(const float4*)&xs[b][4 * j];
    #pragma unroll
    for (int i = 0; i < 4; ++i) {
      float4 w4 = *(const float4*)(wbase + (size_t)i * D_ + 4 * j);
      acc[i] += w4.x * x4.x + w4.y * x4.y + w4.z * x4.z + w4.w * x4.w;
    }
  }
  float4 o0 = {acc[0], acc[1], acc[2], acc[3]};
  *(float4*)(P.part2 + ((size_t)b * 8 + kc) * D_ + et * 64 + eg * 4) = o0;
}

// ------- post: x6 = relu(sum(part2)+fb5)+xr ; post_w-chunk GEMM -> part3; XCD 1-D grid -------
__global__ __launch_bounds__(512, 2) void k_post(Params P) {
  const int g = blockIdx.x, t = threadIdx.x;
  const int et = g >> 3, kc = g & 7;
  __shared__ float xs[32][260];
  const float* fb5 = P.fc_b + (size_t)(L_ - 1) * D_;
  #pragma unroll
  for (int r = 0; r < 16; ++r) {
    int flat = r * 512 + t;
    int bb = flat >> 8, j = flat & 255;
    int col = kc * 256 + j;
    float a = fb5[col];
    #pragma unroll
    for (int kcp = 0; kcp < 8; ++kcp)
      a += P.part2[((size_t)bb * 8 + kcp) * D_ + col];
    xs[bb][j] = fmaxf(a, 0.f) + P.xr[(size_t)bb * D_ + col];
  }
  __syncthreads();
  int b = t & 31, eg = t >> 5;
  const float* wbase = P.post_w + (size_t)(et * 64 + eg * 4) * D_ + kc * 256;
  float acc[4] = {0.f, 0.f, 0.f, 0.f};
  for (int j = 0; j < 64; ++j) {
    float4 x4 = *(const float4*)&xs[b][4 * j];
    #pragma unroll
    for (int i = 0; i < 4; ++i) {
      float4 w4 = *(const float4*)(wbase + (size_t)i * D_ + 4 * j);
      acc[i] += w4.x * x4.x + w4.y * x4.y + w4.z * x4.z + w4.w * x4.w;
    }
  }
  float4 o0 = {acc[0], acc[1], acc[2], acc[3]};
  *(float4*)(P.part3 + ((size_t)b * 8 + kc) * D_ + et * 64 + eg * 4) = o0;
}

// ------- heads: hid = relu(sum(part3)+pb); actor/critic dots -------
__global__ __launch_bounds__(512) void k_heads(Params P) {
  const int b = blockIdx.x, t = threadIdx.x;
  const int lane = t & 63, wv = t >> 6;
  __shared__ float smem[D_];
  {
    float4 a = ((const float4*)P.post_b)[t];
    #pragma unroll
    for (int kcp = 0; kcp < 8; ++kcp) {
      float4 p = ((const float4*)(P.part3 + ((size_t)b * 8 + kcp) * D_))[t];
      a.x += p.x; a.y += p.y; a.z += p.z; a.w += p.w;
    }
    a.x = fmaxf(a.x, 0.f); a.y = fmaxf(a.y, 0.f);
    a.z = fmaxf(a.z, 0.f); a.w = fmaxf(a.w, 0.f);
    ((float4*)smem)[t] = a;
  }
  __syncthreads();
  for (int j = wv; j < A_ + 1; j += 8) {
    const float* wr = (j < A_) ? (P.act_w + (size_t)j * D_) : P.cri_w;
    float acc = 0.f;
    for (int i = lane; i < D_ / 4; i += 64) {
      float4 w4 = ((const float4*)wr)[i];
      float4 xv = ((const float4*)smem)[i];
      acc += w4.x * xv.x + w4.y * xv.y + w4.z * xv.z + w4.w * xv.w;
    }
    acc = wsum64(acc);
    if (lane == 0)
      P.out[b * (A_ + 1) + j] = acc + ((j < A_) ? P.act_b[j] : P.cri_b[0]);
  }
}

} // namespace

extern "C" void kernel_launch(void* const* d_in, const int* in_sizes, int n_in,
                              void* d_out, int out_size, void* d_ws, size_t ws_size,
                              hipStream_t stream) {
  (void)in_sizes; (void)n_in; (void)out_size; (void)ws_size;
  Params p;
  p.x      = (const float*)d_in[0];
  p.mem    = (const float*)d_in[1];
  p.mask   = (const int*)d_in[2];
  p.midx   = (const int*)d_in[3];
  p.enc_w  = (const float*)d_in[4];
  p.enc_b  = (const float*)d_in[5];
  p.lnq_g  = (const float*)d_in[6];
  p.lnq_b  = (const float*)d_in[7];
  p.lnkv_g = (const float*)d_in[8];
  p.lnkv_b = (const float*)d_in[9];
  p.lnat_g = (const float*)d_in[10];
  p.lnat_b = (const float*)d_in[11];
  p.wq     = (const float*)d_in[12];
  p.wk     = (const float*)d_in[13];
  p.wv     = (const float*)d_in[14];
  p.wo     = (const float*)d_in[15];
  p.bo     = (const float*)d_in[16];
  p.fc_w   = (const float*)d_in[17];
  p.fc_b   = (const float*)d_in[18];
  p.post_w = (const float*)d_in[19];
  p.post_b = (const float*)d_in[20];
  p.act_w  = (const float*)d_in[21];
  p.act_b  = (const float*)d_in[22];
  p.cri_w  = (const float*)d_in[23];
  p.cri_b  = (const float*)d_in[24];
  p.out    = (float*)d_out;

  float* ws = (float*)d_ws;
  size_t off = 0;
  p.pe    = ws + off; off += (size_t)MAXS_ * D_;
  p.h     = ws + off; off += (size_t)B_ * D_;
  p.xr    = ws + off; off += (size_t)B_ * D_;
  p.part  = ws + off; off += (size_t)B_ * 8 * D_;
  p.part2 = ws + off; off += (size_t)B_ * 8 * D_;
  p.part3 = ws + off; off += (size_t)B_ * 8 * D_;
  p.pm    = ws + off; off += (size_t)B_ * H_ * NCH;
  p.ps    = ws + off; off += (size_t)B_ * H_ * NCH;
  p.pctx  = ws + off; off += (size_t)B_ * H_ * NCH * HD_;

  hipLaunchKernelGGL(k_peenc, dim3(256), dim3(512), 0, stream, p);
  for (int l = 0; l < L_; ++l) {
    hipLaunchKernelGGL(k_attn, dim3(B_, NCH), dim3(512), 0, stream, p, l);
    hipLaunchKernelGGL(k_wo, dim3(256), dim3(512), 0, stream, p, l);
    hipLaunchKernelGGL(k_fc, dim3(256), dim3(512), 0, stream, p, l);
  }
  hipLaunchKernelGGL(k_post, dim3(256), dim3(512), 0, stream, p);
  hipLaunchKernelGGL(k_heads, dim3(B_), dim3(512), 0, stream, p);
}